// Round 1
// baseline (330.495 us; speedup 1.0000x reference)
//
#include <hip/hip_runtime.h>

typedef _Float16 f16;
typedef _Float16 f16x4 __attribute__((ext_vector_type(4)));
typedef _Float16 f16x8 __attribute__((ext_vector_type(8)));
typedef float    f32x4 __attribute__((ext_vector_type(4)));

#define MFMA16(a,b,c) __builtin_amdgcn_mfma_f32_16x16x32_f16((a),(b),(c),0,0,0)

#define LATENT 64
#define HIDDEN 128

// A-fragment of W[out][K] for out-tile `tile`, k-chunk kf (32 wide).
// Layout for mfma_f32_16x16x32_f16 A: row = lane%16, k = kf*32 + 8*(lane/16)+j
__device__ __forceinline__ f16x8 load_afrag(const float* __restrict__ W, int K,
                                            int tile, int kf, int lane) {
  const int row = tile * 16 + (lane & 15);
  const int k0  = kf * 32 + (lane >> 4) * 8;
  const float* p = W + row * K + k0;
  f16x8 r;
#pragma unroll
  for (int j = 0; j < 8; ++j) r[j] = (f16)p[j];
  return r;
}

// B-fragment: X^T[k][b] where LDS buf holds activations [16 batch rows][dims] f16,
// XOR-swizzled: byte_off_in_row ^= (b&7)<<4.  b = lane%16, k = k0 + 8*(lane/16)+j.
__device__ __forceinline__ f16x8 bfrag(const f16* buf, int rowb, int k0, int lane) {
  const int b  = lane & 15;
  const int kk = k0 + (lane >> 4) * 8;
  const int off = b * rowb + ((kk * 2) ^ ((b & 7) << 4));
  return *(const f16x8*)((const char*)buf + off);
}

// Write one D-tile (f32x4 -> f16x4) to activation LDS buffer, same swizzle.
// D layout: b = lane%16, dims dbase..dbase+3 where dbase = tile*16 + 4*(lane/16).
__device__ __forceinline__ void dwrite(f16* buf, int rowb, int dbase, f32x4 v, int lane) {
  const int b = lane & 15;
  f16x4 h;
#pragma unroll
  for (int i = 0; i < 4; ++i) h[i] = (f16)v[i];
  const int off = b * rowb + ((dbase * 2) ^ ((b & 7) << 4));
  *(f16x4*)((char*)buf + off) = h;
}

__device__ __forceinline__ f32x4 elu4(f32x4 v) {
#pragma unroll
  for (int i = 0; i < 4; ++i) v[i] = v[i] > 0.f ? v[i] : (__expf(v[i]) - 1.f);
  return v;
}

__global__ __launch_bounds__(256, 1)
void node_rk4_kernel(const float* __restrict__ z0,   const float* __restrict__ tg,
                     const float* __restrict__ fc1w, const float* __restrict__ fc1b,
                     const float* __restrict__ fc2w, const float* __restrict__ fc2b,
                     const float* __restrict__ fc3w, const float* __restrict__ fc3b,
                     const float* __restrict__ l2hw, const float* __restrict__ l2hb,
                     const float* __restrict__ h2ow, const float* __restrict__ h2ob,
                     float* __restrict__ out, int Btot, int T) {
  // activations staged per layer, f16, XOR-swizzled rows
  __shared__ __align__(16) f16 xbuf[16 * 64];    // current f-input (latent)
  __shared__ __align__(16) f16 h1buf[16 * 128];  // hidden1 / decoder-hidden
  __shared__ __align__(16) f16 h2buf[16 * 128];  // hidden2
  __shared__ __align__(16) float outst[16 * 64]; // decoder output staging (f32)

  const int tid  = threadIdx.x;
  const int lane = tid & 63;
  const int wv   = tid >> 6;     // wave 0..3: owns out-dims [32w,32w+32) hidden, [16w,16w+16) latent
  const int grp  = lane >> 4;
  const int bcol = lane & 15;
  const int row0 = blockIdx.x * 16;
  const int dz   = wv * 16 + grp * 4;  // latent dims owned by this lane (D-tile rows)

  // ---- one-time: weights -> register fragments (f16), biases -> registers ----
  f16x8 a1[2][2], aL[2][2], a2[2][4], a3[4], aO[4];
#pragma unroll
  for (int ot = 0; ot < 2; ++ot) {
#pragma unroll
    for (int kf = 0; kf < 2; ++kf) {
      a1[ot][kf] = load_afrag(fc1w, 64, 2 * wv + ot, kf, lane);
      aL[ot][kf] = load_afrag(l2hw, 64, 2 * wv + ot, kf, lane);
    }
#pragma unroll
    for (int kf = 0; kf < 4; ++kf) a2[ot][kf] = load_afrag(fc2w, 128, 2 * wv + ot, kf, lane);
  }
#pragma unroll
  for (int kf = 0; kf < 4; ++kf) {
    a3[kf] = load_afrag(fc3w, 128, wv, kf, lane);
    aO[kf] = load_afrag(h2ow, 128, wv, kf, lane);
  }

  f32x4 b1[2], b2[2], bL[2], b3, bO;
#pragma unroll
  for (int ot = 0; ot < 2; ++ot) {
    const int d = (2 * wv + ot) * 16 + grp * 4;
    b1[ot] = *(const f32x4*)(fc1b + d);
    b2[ot] = *(const f32x4*)(fc2b + d);
    bL[ot] = *(const f32x4*)(l2hb + d);
  }
  b3 = *(const f32x4*)(fc3b + dz);
  bO = *(const f32x4*)(h2ob + dz);

  // ---- z state: this lane holds z[row0+bcol][dz..dz+3] in D layout ----
  f32x4 z = *(const f32x4*)(z0 + (size_t)(row0 + bcol) * LATENT + dz);

  // f(z) for the staged xbuf; 2 internal barriers
  auto feval = [&]() -> f32x4 {
    const f16x8 v0 = bfrag(xbuf, 128, 0, lane);
    const f16x8 v1 = bfrag(xbuf, 128, 32, lane);
#pragma unroll
    for (int ot = 0; ot < 2; ++ot) {
      f32x4 d = {0.f, 0.f, 0.f, 0.f};
      d = MFMA16(a1[ot][0], v0, d);
      d = MFMA16(a1[ot][1], v1, d);
      d += b1[ot];
      d = elu4(d);
      dwrite(h1buf, 256, (2 * wv + ot) * 16 + grp * 4, d, lane);
    }
    __syncthreads();
#pragma unroll
    for (int ot = 0; ot < 2; ++ot) {
      f32x4 d = {0.f, 0.f, 0.f, 0.f};
#pragma unroll
      for (int kf = 0; kf < 4; ++kf) d = MFMA16(a2[ot][kf], bfrag(h1buf, 256, kf * 32, lane), d);
      d += b2[ot];
      d = elu4(d);
      dwrite(h2buf, 256, (2 * wv + ot) * 16 + grp * 4, d, lane);
    }
    __syncthreads();
    f32x4 d = {0.f, 0.f, 0.f, 0.f};
#pragma unroll
    for (int kf = 0; kf < 4; ++kf) d = MFMA16(a3[kf], bfrag(h2buf, 256, kf * 32, lane), d);
    d += b3;
    return d;
  };

  for (int s = 0;; ++s) {
    // ---- stage x = z (also the k1 input) ----
    dwrite(xbuf, 128, dz, z, lane);
    __syncthreads();

    // ---- decoder: out[s] = h2o(relu(l2h(z))) ----
    {
      const f16x8 x0 = bfrag(xbuf, 128, 0, lane);
      const f16x8 x1 = bfrag(xbuf, 128, 32, lane);
#pragma unroll
      for (int ot = 0; ot < 2; ++ot) {
        f32x4 d = {0.f, 0.f, 0.f, 0.f};
        d = MFMA16(aL[ot][0], x0, d);
        d = MFMA16(aL[ot][1], x1, d);
        d += bL[ot];
#pragma unroll
        for (int i = 0; i < 4; ++i) d[i] = fmaxf(d[i], 0.f);
        dwrite(h1buf, 256, (2 * wv + ot) * 16 + grp * 4, d, lane);
      }
      __syncthreads();
      f32x4 o = {0.f, 0.f, 0.f, 0.f};
#pragma unroll
      for (int kf = 0; kf < 4; ++kf) o = MFMA16(aO[kf], bfrag(h1buf, 256, kf * 32, lane), o);
      o += bO;
      const int off = bcol * 256 + ((dz * 4) ^ ((bcol & 7) << 4));
      *(f32x4*)((char*)outst + off) = o;
    }
    __syncthreads();
    {  // coalesced global write: 256 threads x float4 = 16 rows x 64 dims
      const int flat = tid * 4;
      const int b = flat >> 6;
      const int d = flat & 63;
      const int off = b * 256 + ((d * 4) ^ ((b & 7) << 4));
      f32x4 v = *(const f32x4*)((const char*)outst + off);
      *(f32x4*)(out + ((size_t)s * Btot + row0 + b) * LATENT + d) = v;
    }
    if (s == T - 1) break;

    const float dt = tg[s + 1] - tg[s];

    // ---- RK4 (xbuf already holds z) ----
    f32x4 k = feval();  // k1
    f32x4 acc = k;
    f32x4 xs;
#pragma unroll
    for (int i = 0; i < 4; ++i) xs[i] = z[i] + 0.5f * dt * k[i];
    dwrite(xbuf, 128, dz, xs, lane);
    __syncthreads();
    k = feval();  // k2
#pragma unroll
    for (int i = 0; i < 4; ++i) { acc[i] += 2.f * k[i]; xs[i] = z[i] + 0.5f * dt * k[i]; }
    dwrite(xbuf, 128, dz, xs, lane);
    __syncthreads();
    k = feval();  // k3
#pragma unroll
    for (int i = 0; i < 4; ++i) { acc[i] += 2.f * k[i]; xs[i] = z[i] + dt * k[i]; }
    dwrite(xbuf, 128, dz, xs, lane);
    __syncthreads();
    k = feval();  // k4
#pragma unroll
    for (int i = 0; i < 4; ++i) z[i] += (dt / 6.f) * (acc[i] + k[i]);
  }
}

extern "C" void kernel_launch(void* const* d_in, const int* in_sizes, int n_in,
                              void* d_out, int out_size, void* d_ws, size_t ws_size,
                              hipStream_t stream) {
  const float* z0   = (const float*)d_in[0];
  const float* tg   = (const float*)d_in[1];
  const float* fc1w = (const float*)d_in[2];
  const float* fc1b = (const float*)d_in[3];
  const float* fc2w = (const float*)d_in[4];
  const float* fc2b = (const float*)d_in[5];
  const float* fc3w = (const float*)d_in[6];
  const float* fc3b = (const float*)d_in[7];
  const float* l2hw = (const float*)d_in[8];
  const float* l2hb = (const float*)d_in[9];
  const float* h2ow = (const float*)d_in[10];
  const float* h2ob = (const float*)d_in[11];
  float* out = (float*)d_out;

  const int Btot = in_sizes[0] / LATENT;  // 4096
  const int T    = in_sizes[1];           // 100

  dim3 grid(Btot / 16), block(256);
  node_rk4_kernel<<<grid, block, 0, stream>>>(z0, tg, fc1w, fc1b, fc2w, fc2b,
                                              fc3w, fc3b, l2hw, l2hb, h2ow, h2ob,
                                              out, Btot, T);
}